// Round 10
// baseline (47.537 us; speedup 1.0000x reference)
//
#include <hip/hip_runtime.h>
#include <hip/hip_bf16.h>

// Problem dims (fixed by the reference): B=64, T=2048, D=256
#define BB  64
#define TT  2048
#define DD  256
#define EPSV 1e-7f
#define TILE_R 32    // rows per tile
#define NTILE  8     // tiles per block
#define NBLK   512   // blocks: NBLK*NTILE*TILE_R == BB*TT
#define PITCH  528   // LDS row pitch (bytes): 528 mod 128 = 16 -> bank-spread, additive addressing
#define TILEB  16896 // 32 * 528

#define TANH_PRE 2.8853900817779268f   // 2*log2(e): folded into W and bias
#define LOG2E    1.4426950408889634f   // folded into attend_w

typedef __attribute__((ext_vector_type(8))) short bf16x8;   // MFMA A/B fragment (4 VGPR)
typedef __attribute__((ext_vector_type(4))) float f32x4;    // MFMA C/D fragment

__device__ __forceinline__ ushort f2bf(float f) {           // RNE (prep only)
    union { float f; unsigned u; } v; v.f = f;
    unsigned u = v.u;
    unsigned r = (u + 0x7FFFu + ((u >> 16) & 1u)) >> 16;
    return (ushort)r;
}

__device__ __forceinline__ float bf2f(unsigned h16) {       // low 16 bits = bf16
    union { unsigned u; float f; } v; v.u = h16 << 16;
    return v.f;
}

// pack two f32 -> two bf16 (round-half-up): [bf(lo), bf(hi)]
__device__ __forceinline__ unsigned pkbf(float lo, float hi) {
    union { float f; unsigned u; } a, b;
    a.f = lo; b.f = hi;
    return __builtin_amdgcn_perm(b.u + 0x8000u, a.u + 0x8000u, 0x07060302u);
}

// tanh(t) where y = 2*log2(e)*t (scaling pre-folded into MFMA operands):
// tanh(t) = 1 - 2/(e^{2t}+1) = 1 - 2*rcp(exp2(y)+1)   -> exp, add, rcp, fma
__device__ __forceinline__ float tanh_pre(float y) {
    float e = exp2f(y);
    return fmaf(-2.0f, __builtin_amdgcn_rcpf(e + 1.0f), 1.0f);
}

// sum over the 16-lane DPP row via rotations (pure VALU, no LDS traffic)
template<int CTRL>
__device__ __forceinline__ float dpp_rot_add(float x) {
    union { float f; int i; } a; a.f = x;
    int r = __builtin_amdgcn_update_dpp(0, a.i, CTRL, 0xF, 0xF, true);
    union { int i; float f; } b; b.i = r;
    return x + b.f;
}
__device__ __forceinline__ float row16_sum(float x) {
    x = dpp_rot_add<0x121>(x);   // row_ror:1
    x = dpp_rot_add<0x122>(x);   // row_ror:2
    x = dpp_rot_add<0x124>(x);   // row_ror:4
    x = dpp_rot_add<0x128>(x);   // row_ror:8
    return x;                    // all 16 lanes hold the row sum
}

// ---------------------------------------------------------------------------
// prep: blocks 0..511   -> bias partials (block b*8+q covers d in [q*32, q*32+32))
//       blocks 512..543 -> W_frag: context_w (f32) * 2*log2(e) -> bf16 MFMA B-frag order
// ---------------------------------------------------------------------------
__global__ __launch_bounds__(256) void prep_kernel(
    const float* __restrict__ aspect, const float* __restrict__ sentence,
    const float* __restrict__ context_w, const float* __restrict__ aspect_w,
    const float* __restrict__ sent_w,
    float* __restrict__ bias_part, ushort* __restrict__ wfrag_ws)
{
    const int blk = blockIdx.x, tid = threadIdx.x;
    if (blk < 512) {
        const int b = blk >> 3, q = blk & 7, e = tid;
        float s = 0.f;
        #pragma unroll 4
        for (int dd = 0; dd < 32; ++dd) {
            const int d = q * 32 + dd;
            s = fmaf(aspect[b * DD + d],   aspect_w[d * DD + e], s);
            s = fmaf(sentence[b * DD + d], sent_w[d * DD + e],   s);
        }
        bias_part[blk * DD + e] = s;
    } else {
        const int flat = (blk - 512) * 256 + tid;    // 0..8191
        const int lane = flat & 63;
        const int kn   = flat >> 6;
        const int kk   = kn >> 4;
        const int n    = kn & 15;
        const int krow = kk * 32 + ((lane >> 4) << 3);
        const int col  = n * 16 + (lane & 15);
        bf16x8 v;
        #pragma unroll
        for (int j = 0; j < 8; ++j)
            v[j] = (short)f2bf(context_w[(size_t)(krow + j) * DD + col] * TANH_PRE);
        *reinterpret_cast<bf16x8*>(wfrag_ws + (size_t)flat * 8) = v;
    }
}

// ---------------------------------------------------------------------------
// attn_main: 512 blocks x 512 thr (8 waves), 8 tiles of 32 rows.
// QUAD-buffered bf16 tiles (pitch 528 -> additive bank-spread addressing, all
// A-reads at immediate offsets), ONE barrier per tile, evals+wsum DEFERRED:
//   [wsum(it-1) | convert(it+1) | loads(it+2) | GEMM(it) | tanh->gpartT] BAR
// tanh/exp scaling pre-folded into W/bias/aw (4-op tanh, exp2 ev). No setprio.
// ---------------------------------------------------------------------------
__global__ __launch_bounds__(512, 2) void attn_main(
    const float* __restrict__ ctx, const int* __restrict__ mask,
    const float* __restrict__ attend_w,
    const float* __restrict__ bias_part, const ushort* __restrict__ wfrag_ws,
    float* __restrict__ partial_ws, float* __restrict__ esum_ws)
{
    __shared__ __align__(16) char bfb[4][TILEB];   // 4 x 16.9KB bf16 tiles
    __shared__ float gpartT[2][8][TILE_R];         // [phase][cg][row]
    __shared__ float bias_lds[256];
    __shared__ float aw_lds[256];
    __shared__ float mask_lds[256];

    const int tid  = threadIdx.x;
    const int wave = tid >> 6;
    const int lane = tid & 63;
    const int blk  = blockIdx.x;
    const int b    = blk >> 3;               // 8 blocks per batch element
    const int cg   = wave;                   // col group (32 cols)
    const int l15  = lane & 15, hi = lane >> 4;

    if (tid < 256) {
        float bs = 0.f;
        #pragma unroll
        for (int q = 0; q < 8; ++q) bs += bias_part[(b * 8 + q) * DD + tid];
        bias_lds[tid] = bs * TANH_PRE;
    } else {
        const int m = tid - 256;
        aw_lds[m]   = attend_w[m] * LOG2E;
        mask_lds[m] = (float)mask[blk * 256 + m];
    }

    // ---- preload this wave's 16 B-fragments (cols cg*32 .. +31): 64 VGPR ----
    bf16x8 Bf[8][2];
    {
        const bf16x8* wf = reinterpret_cast<const bf16x8*>(wfrag_ws);
        #pragma unroll
        for (int kk = 0; kk < 8; ++kk) {
            Bf[kk][0] = wf[(kk * 16 + cg * 2 + 0) * 64 + lane];
            Bf[kk][1] = wf[(kk * 16 + cg * 2 + 1) * 64 + lane];
        }
    }

    const float4* src = reinterpret_cast<const float4*>(ctx);
    // convert-phase destinations (additive, no XOR)
    const int crow0 = tid >> 5,          c80 = tid & 31;
    const int crow1 = (512 + tid) >> 5,  c81 = (512 + tid) & 31;
    const int coff0 = crow0 * PITCH + c80 * 16;
    const int coff1 = crow1 * PITCH + c81 * 16;
    // GEMM A-read lane base; reads at imm rt*8448 + kk*64
    const int abase = l15 * PITCH + hi * 16;
    // wsum read base; reads at imm rr*PITCH
    const int wbase = wave * 4 * PITCH + lane * 8;

    // ---- prologue: load tile 0, convert -> buf0, issue tile 1 loads ----
    float4 sreg[4];
    {
        const size_t base4 = (size_t)(blk * NTILE) * 2048;
        #pragma unroll
        for (int i = 0; i < 2; ++i) {
            const int c = i * 512 + tid;
            sreg[2 * i + 0] = src[base4 + 2 * c + 0];
            sreg[2 * i + 1] = src[base4 + 2 * c + 1];
        }
        char* dst = bfb[0];
        #pragma unroll
        for (int i = 0; i < 2; ++i) {
            uint4 u;
            u.x = pkbf(sreg[2 * i].x,     sreg[2 * i].y);
            u.y = pkbf(sreg[2 * i].z,     sreg[2 * i].w);
            u.z = pkbf(sreg[2 * i + 1].x, sreg[2 * i + 1].y);
            u.w = pkbf(sreg[2 * i + 1].z, sreg[2 * i + 1].w);
            *reinterpret_cast<uint4*>(dst + (i ? coff1 : coff0)) = u;
        }
        const size_t b1 = (size_t)(blk * NTILE + 1) * 2048;
        #pragma unroll
        for (int i = 0; i < 2; ++i) {
            const int c = i * 512 + tid;
            sreg[2 * i + 0] = src[b1 + 2 * c + 0];
            sreg[2 * i + 1] = src[b1 + 2 * c + 1];
        }
    }
    __syncthreads();

    // loop-invariant epilogue constants
    const int c0 = cg * 32 + l15, c1 = c0 + 16;
    const float bs0 = bias_lds[c0], awc0 = aw_lds[c0];
    const float bs1 = bias_lds[c1], awc1 = aw_lds[c1];

    float accd[4] = {0.f, 0.f, 0.f, 0.f};
    float es_acc = 0.f;

    // deferred evals + weighted sum for tile t (reads gpartT[t&1], bfb[t&3])
    auto do_wsum = [&](int t) {
        const char* pb = bfb[t & 3] + wbase;
        const int gp = t & 1;
        const int erow = lane & 31;
        float gsum = 0.f;
        #pragma unroll
        for (int c = 0; c < 8; ++c) gsum += gpartT[gp][c][erow];
        const float ev = exp2f(gsum) * mask_lds[t * TILE_R + erow];
        es_acc += (lane < 32) ? ev : 0.f;
        #pragma unroll
        for (int rr = 0; rr < 4; ++rr) {
            const int r = wave * 4 + rr;
            const float e = __shfl(ev, r);   // uniform index -> readlane broadcast
            const uint2 hv = *reinterpret_cast<const uint2*>(pb + rr * PITCH);
            accd[0] = fmaf(bf2f(hv.x & 0xffffu), e, accd[0]);
            accd[1] = fmaf(bf2f(hv.x >> 16),     e, accd[1]);
            accd[2] = fmaf(bf2f(hv.y & 0xffffu), e, accd[2]);
            accd[3] = fmaf(bf2f(hv.y >> 16),     e, accd[3]);
        }
    };

    #pragma unroll
    for (int it = 0; it < NTILE; ++it) {
        const char* lb = bfb[it & 3];

        // ---- (0) deferred evals+wsum for tile it-1 ----
        if (it > 0) do_wsum(it - 1);

        // ---- (1) convert sreg (tile it+1 data) -> buf[(it+1)&3] ----
        if (it + 1 < NTILE) {
            char* dst = bfb[(it + 1) & 3];
            #pragma unroll
            for (int i = 0; i < 2; ++i) {
                uint4 u;
                u.x = pkbf(sreg[2 * i].x,     sreg[2 * i].y);
                u.y = pkbf(sreg[2 * i].z,     sreg[2 * i].w);
                u.z = pkbf(sreg[2 * i + 1].x, sreg[2 * i + 1].y);
                u.w = pkbf(sreg[2 * i + 1].z, sreg[2 * i + 1].w);
                *reinterpret_cast<uint4*>(dst + (i ? coff1 : coff0)) = u;
            }
        }
        // ---- (2) issue tile it+2 global loads ----
        if (it + 2 < NTILE) {
            const size_t base4 = (size_t)(blk * NTILE + it + 2) * 2048;
            #pragma unroll
            for (int i = 0; i < 2; ++i) {
                const int c = i * 512 + tid;
                sreg[2 * i + 0] = src[base4 + 2 * c + 0];
                sreg[2 * i + 1] = src[base4 + 2 * c + 1];
            }
        }

        // ---- (3) GEMM: 32 rows x this wave's 32 cols, K=256 ----
        f32x4 acc[2][2];
        #pragma unroll
        for (int rt = 0; rt < 2; ++rt) {
            acc[rt][0] = (f32x4){0.f, 0.f, 0.f, 0.f};
            acc[rt][1] = (f32x4){0.f, 0.f, 0.f, 0.f};
        }
        {
            const char* ab = lb + abase;
            #pragma unroll
            for (int rt = 0; rt < 2; ++rt) {
                #pragma unroll
                for (int kk = 0; kk < 8; ++kk) {
                    const bf16x8 a = *reinterpret_cast<const bf16x8*>(
                        ab + rt * 16 * PITCH + kk * 64);
                    acc[rt][0] = __builtin_amdgcn_mfma_f32_16x16x32_bf16(a, Bf[kk][0], acc[rt][0], 0, 0, 0);
                    acc[rt][1] = __builtin_amdgcn_mfma_f32_16x16x32_bf16(a, Bf[kk][1], acc[rt][1], 0, 0, 0);
                }
            }
        }

        // ---- (4) tanh epilogue + DPP reduce -> gpartT[it&1][cg][*] ----
        const int gp = it & 1;
        #pragma unroll
        for (int rt = 0; rt < 2; ++rt) {
            float g0 = row16_sum(tanh_pre(acc[rt][0][0] + bs0) * awc0
                               + tanh_pre(acc[rt][1][0] + bs1) * awc1);
            float g1 = row16_sum(tanh_pre(acc[rt][0][1] + bs0) * awc0
                               + tanh_pre(acc[rt][1][1] + bs1) * awc1);
            float g2 = row16_sum(tanh_pre(acc[rt][0][2] + bs0) * awc0
                               + tanh_pre(acc[rt][1][2] + bs1) * awc1);
            float g3 = row16_sum(tanh_pre(acc[rt][0][3] + bs0) * awc0
                               + tanh_pre(acc[rt][1][3] + bs1) * awc1);
            if (l15 == 0) {
                const int r = rt * 16 + (hi << 2);
                *reinterpret_cast<float4*>(&gpartT[gp][cg][r]) = (float4){g0, g1, g2, g3};
            }
        }
        __syncthreads();   // the ONLY barrier per tile
    }

    // ---- drain: evals+wsum for the last tile ----
    do_wsum(NTILE - 1);

    // ---- block epilogue: part_d overlaid on bfb[0] (dead after do_wsum(4)) ----
    {
        float* part_d = reinterpret_cast<float*>(bfb[0]);    // [8][256]
        *reinterpret_cast<float4*>(&part_d[wave * 256 + lane * 4]) =
            (float4){accd[0], accd[1], accd[2], accd[3]};
    }
    __syncthreads();
    if (tid < 256) {
        const float* part_d = reinterpret_cast<const float*>(bfb[0]);
        float s = 0.f;
        #pragma unroll
        for (int w = 0; w < 8; ++w) s += part_d[w * 256 + tid];
        partial_ws[blk * DD + tid] = s;
    }
    if (wave == 0) {
        float s = row16_sum(es_acc);
        s += __shfl_xor(s, 16);
        if (lane == 0) esum_ws[blk] = s;
    }
}

// ---------------------------------------------------------------------------
// finalize: out[b,d] = (sum_i partial) / (sum_i esum + EPS) + sentence[b,d]
// ---------------------------------------------------------------------------
__global__ __launch_bounds__(256) void finalize_kernel(
    const float* __restrict__ sentence, const float* __restrict__ partial_ws,
    const float* __restrict__ esum_ws, float* __restrict__ out)
{
    const int b = blockIdx.x, d = threadIdx.x;
    float es = 0.f, s = 0.f;
    #pragma unroll
    for (int i = 0; i < 8; ++i) {
        es += esum_ws[b * 8 + i];
        s  += partial_ws[(size_t)(b * 8 + i) * DD + d];
    }
    out[b * DD + d] = s / (es + EPSV) + sentence[b * DD + d];
}

extern "C" void kernel_launch(void* const* d_in, const int* in_sizes, int n_in,
                              void* d_out, int out_size, void* d_ws, size_t ws_size,
                              hipStream_t stream)
{
    const float* ctx       = (const float*)d_in[0];
    const float* aspect    = (const float*)d_in[1];
    const float* sentence  = (const float*)d_in[2];
    const int*   mask      = (const int*)  d_in[3];
    const float* context_w = (const float*)d_in[4];
    const float* aspect_w  = (const float*)d_in[5];
    const float* sent_w    = (const float*)d_in[6];
    const float* attend_w  = (const float*)d_in[7];
    float* out = (float*)d_out;

    char* ws = (char*)d_ws;
    ushort* wfrag_ws   = (ushort*)(ws);                           // 131072 B
    float*  bias_part  = (float*) (ws + 131072);                  // 524288 B
    float*  esum_ws    = (float*) (ws + 131072 + 524288);         //   2048 B
    float*  partial_ws = (float*) (ws + 131072 + 524288 + 2048);  // 524288 B

    prep_kernel<<<544, 256, 0, stream>>>(aspect, sentence, context_w, aspect_w, sent_w,
                                         bias_part, wfrag_ws);
    attn_main<<<NBLK, 512, 0, stream>>>(ctx, mask, attend_w, bias_part, wfrag_ws,
                                        partial_ws, esum_ws);
    finalize_kernel<<<BB, 256, 0, stream>>>(sentence, partial_ws, esum_ws, out);
}

// Round 11
// 45.052 us; speedup vs baseline: 1.0552x; 1.0552x over previous
//
#include <hip/hip_runtime.h>
#include <hip/hip_bf16.h>

// Problem dims (fixed by the reference): B=64, T=2048, D=256
#define BB  64
#define TT  2048
#define DD  256
#define EPSV 1e-7f
#define TILE_R 32    // rows per tile
#define NTILE  8     // tiles per block
#define NBLK   512   // blocks: NBLK*NTILE*TILE_R == BB*TT
#define PITCH  528   // LDS row pitch (bytes): bank-spread equal to XOR layout, additive addressing
#define TILEB  16896 // 32 * 528

#define TANH_PRE 2.8853900817779268f   // 2*log2(e): folded into W and bias
#define LOG2E    1.4426950408889634f   // folded into attend_w

typedef __attribute__((ext_vector_type(8))) short bf16x8;   // MFMA A/B fragment (4 VGPR)
typedef __attribute__((ext_vector_type(4))) float f32x4;    // MFMA C/D fragment

__device__ __forceinline__ ushort f2bf(float f) {           // RNE (prep only)
    union { float f; unsigned u; } v; v.f = f;
    unsigned u = v.u;
    unsigned r = (u + 0x7FFFu + ((u >> 16) & 1u)) >> 16;
    return (ushort)r;
}

__device__ __forceinline__ float bf2f(unsigned h16) {       // low 16 bits = bf16
    union { unsigned u; float f; } v; v.u = h16 << 16;
    return v.f;
}

// pack two f32 -> two bf16 (round-half-up): [bf(lo), bf(hi)]
__device__ __forceinline__ unsigned pkbf(float lo, float hi) {
    union { float f; unsigned u; } a, b;
    a.f = lo; b.f = hi;
    return __builtin_amdgcn_perm(b.u + 0x8000u, a.u + 0x8000u, 0x07060302u);
}

// tanh(t) where y = 2*log2(e)*t (scaling pre-folded into MFMA operands):
// tanh(t) = 1 - 2/(e^{2t}+1) = 1 - 2*rcp(exp2(y)+1)
// __builtin_amdgcn_exp2f = raw v_exp_f32 (same HW inst __expf uses; NOT the
// exp2f libcall, which R10 showed costs a guarded __ocml sequence).
__device__ __forceinline__ float tanh_pre(float y) {
    float e = __builtin_amdgcn_exp2f(y);
    return fmaf(-2.0f, __builtin_amdgcn_rcpf(e + 1.0f), 1.0f);
}

// sum over the 16-lane DPP row via rotations (pure VALU, no LDS traffic)
template<int CTRL>
__device__ __forceinline__ float dpp_rot_add(float x) {
    union { float f; int i; } a; a.f = x;
    int r = __builtin_amdgcn_update_dpp(0, a.i, CTRL, 0xF, 0xF, true);
    union { int i; float f; } b; b.i = r;
    return x + b.f;
}
__device__ __forceinline__ float row16_sum(float x) {
    x = dpp_rot_add<0x121>(x);   // row_ror:1
    x = dpp_rot_add<0x122>(x);   // row_ror:2
    x = dpp_rot_add<0x124>(x);   // row_ror:4
    x = dpp_rot_add<0x128>(x);   // row_ror:8
    return x;                    // all 16 lanes hold the row sum
}

// ---------------------------------------------------------------------------
// prep: blocks 0..511   -> bias partials (block b*8+q covers d in [q*32, q*32+32))
//       blocks 512..543 -> W_frag: context_w (f32) * 2*log2(e) -> bf16 MFMA B-frag order
// ---------------------------------------------------------------------------
__global__ __launch_bounds__(256) void prep_kernel(
    const float* __restrict__ aspect, const float* __restrict__ sentence,
    const float* __restrict__ context_w, const float* __restrict__ aspect_w,
    const float* __restrict__ sent_w,
    float* __restrict__ bias_part, ushort* __restrict__ wfrag_ws)
{
    const int blk = blockIdx.x, tid = threadIdx.x;
    if (blk < 512) {
        const int b = blk >> 3, q = blk & 7, e = tid;
        float s = 0.f;
        #pragma unroll 4
        for (int dd = 0; dd < 32; ++dd) {
            const int d = q * 32 + dd;
            s = fmaf(aspect[b * DD + d],   aspect_w[d * DD + e], s);
            s = fmaf(sentence[b * DD + d], sent_w[d * DD + e],   s);
        }
        bias_part[blk * DD + e] = s;
    } else {
        const int flat = (blk - 512) * 256 + tid;    // 0..8191
        const int lane = flat & 63;
        const int kn   = flat >> 6;
        const int kk   = kn >> 4;
        const int n    = kn & 15;
        const int krow = kk * 32 + ((lane >> 4) << 3);
        const int col  = n * 16 + (lane & 15);
        bf16x8 v;
        #pragma unroll
        for (int j = 0; j < 8; ++j)
            v[j] = (short)f2bf(context_w[(size_t)(krow + j) * DD + col] * TANH_PRE);
        *reinterpret_cast<bf16x8*>(wfrag_ws + (size_t)flat * 8) = v;
    }
}

// ---------------------------------------------------------------------------
// attn_main: 512 blocks x 512 thr (8 waves), 8 tiles of 32 rows.
// QUAD-buffered bf16 tiles (pitch 528, additive imm addressing), ONE barrier
// per tile, evals+wsum DEFERRED one iteration:
//   [wsum(it-1) | convert(it+1) | loads(it+2) | GEMM(it) | tanh->gpartT] BAR
// Scaling pre-folded into W/bias/aw; HW exp2 everywhere; rolled main loop.
// ---------------------------------------------------------------------------
__global__ __launch_bounds__(512, 2) void attn_main(
    const float* __restrict__ ctx, const int* __restrict__ mask,
    const float* __restrict__ attend_w,
    const float* __restrict__ bias_part, const ushort* __restrict__ wfrag_ws,
    float* __restrict__ partial_ws, float* __restrict__ esum_ws)
{
    __shared__ __align__(16) char bfb[4][TILEB];   // 4 x 16.9KB bf16 tiles
    __shared__ float gpartT[2][8][TILE_R];         // [phase][cg][row]
    __shared__ float bias_lds[256];
    __shared__ float aw_lds[256];
    __shared__ float mask_lds[256];

    const int tid  = threadIdx.x;
    const int wave = tid >> 6;
    const int lane = tid & 63;
    const int blk  = blockIdx.x;
    const int b    = blk >> 3;               // 8 blocks per batch element
    const int cg   = wave;                   // col group (32 cols)
    const int l15  = lane & 15, hi = lane >> 4;

    if (tid < 256) {
        float bs = 0.f;
        #pragma unroll
        for (int q = 0; q < 8; ++q) bs += bias_part[(b * 8 + q) * DD + tid];
        bias_lds[tid] = bs * TANH_PRE;
    } else {
        const int m = tid - 256;
        aw_lds[m]   = attend_w[m] * LOG2E;
        mask_lds[m] = (float)mask[blk * 256 + m];
    }

    // ---- preload this wave's 16 B-fragments (cols cg*32 .. +31): 64 VGPR ----
    bf16x8 Bf[8][2];
    {
        const bf16x8* wf = reinterpret_cast<const bf16x8*>(wfrag_ws);
        #pragma unroll
        for (int kk = 0; kk < 8; ++kk) {
            Bf[kk][0] = wf[(kk * 16 + cg * 2 + 0) * 64 + lane];
            Bf[kk][1] = wf[(kk * 16 + cg * 2 + 1) * 64 + lane];
        }
    }

    const float4* src = reinterpret_cast<const float4*>(ctx);
    // convert-phase destinations (additive, no XOR)
    const int crow0 = tid >> 5,          c80 = tid & 31;
    const int crow1 = (512 + tid) >> 5,  c81 = (512 + tid) & 31;
    const int coff0 = crow0 * PITCH + c80 * 16;
    const int coff1 = crow1 * PITCH + c81 * 16;
    // GEMM A-read lane base; reads at imm rt*16*PITCH + kk*64
    const int abase = l15 * PITCH + hi * 16;
    // wsum read base; reads at imm rr*PITCH
    const int wbase = wave * 4 * PITCH + lane * 8;

    // ---- prologue: load tile 0, convert -> buf0, issue tile 1 loads ----
    float4 sreg[4];
    {
        const size_t base4 = (size_t)(blk * NTILE) * 2048;
        #pragma unroll
        for (int i = 0; i < 2; ++i) {
            const int c = i * 512 + tid;
            sreg[2 * i + 0] = src[base4 + 2 * c + 0];
            sreg[2 * i + 1] = src[base4 + 2 * c + 1];
        }
        char* dst = bfb[0];
        #pragma unroll
        for (int i = 0; i < 2; ++i) {
            uint4 u;
            u.x = pkbf(sreg[2 * i].x,     sreg[2 * i].y);
            u.y = pkbf(sreg[2 * i].z,     sreg[2 * i].w);
            u.z = pkbf(sreg[2 * i + 1].x, sreg[2 * i + 1].y);
            u.w = pkbf(sreg[2 * i + 1].z, sreg[2 * i + 1].w);
            *reinterpret_cast<uint4*>(dst + (i ? coff1 : coff0)) = u;
        }
        const size_t b1 = (size_t)(blk * NTILE + 1) * 2048;
        #pragma unroll
        for (int i = 0; i < 2; ++i) {
            const int c = i * 512 + tid;
            sreg[2 * i + 0] = src[b1 + 2 * c + 0];
            sreg[2 * i + 1] = src[b1 + 2 * c + 1];
        }
    }
    __syncthreads();

    // loop-invariant epilogue constants
    const int c0 = cg * 32 + l15, c1 = c0 + 16;
    const float bs0 = bias_lds[c0], awc0 = aw_lds[c0];
    const float bs1 = bias_lds[c1], awc1 = aw_lds[c1];

    float accd[4] = {0.f, 0.f, 0.f, 0.f};
    float es_acc = 0.f;

    // deferred evals + weighted sum for tile t (reads gpartT[t&1], bfb[t&3])
    auto do_wsum = [&](int t) {
        const char* pb = bfb[t & 3] + wbase;
        const int gp = t & 1;
        const int erow = lane & 31;
        float gsum = 0.f;
        #pragma unroll
        for (int c = 0; c < 8; ++c) gsum += gpartT[gp][c][erow];
        const float ev = __builtin_amdgcn_exp2f(gsum) * mask_lds[t * TILE_R + erow];
        es_acc += (lane < 32) ? ev : 0.f;
        #pragma unroll
        for (int rr = 0; rr < 4; ++rr) {
            const int r = wave * 4 + rr;
            const float e = __shfl(ev, r);   // uniform index -> readlane broadcast
            const uint2 hv = *reinterpret_cast<const uint2*>(pb + rr * PITCH);
            accd[0] = fmaf(bf2f(hv.x & 0xffffu), e, accd[0]);
            accd[1] = fmaf(bf2f(hv.x >> 16),     e, accd[1]);
            accd[2] = fmaf(bf2f(hv.y & 0xffffu), e, accd[2]);
            accd[3] = fmaf(bf2f(hv.y >> 16),     e, accd[3]);
        }
    };

    for (int it = 0; it < NTILE; ++it) {
        const char* lb = bfb[it & 3];

        // ---- (0) deferred evals+wsum for tile it-1 ----
        if (it > 0) do_wsum(it - 1);

        // ---- (1) convert sreg (tile it+1 data) -> buf[(it+1)&3] ----
        if (it + 1 < NTILE) {
            char* dst = bfb[(it + 1) & 3];
            #pragma unroll
            for (int i = 0; i < 2; ++i) {
                uint4 u;
                u.x = pkbf(sreg[2 * i].x,     sreg[2 * i].y);
                u.y = pkbf(sreg[2 * i].z,     sreg[2 * i].w);
                u.z = pkbf(sreg[2 * i + 1].x, sreg[2 * i + 1].y);
                u.w = pkbf(sreg[2 * i + 1].z, sreg[2 * i + 1].w);
                *reinterpret_cast<uint4*>(dst + (i ? coff1 : coff0)) = u;
            }
        }
        // ---- (2) issue tile it+2 global loads ----
        if (it + 2 < NTILE) {
            const size_t base4 = (size_t)(blk * NTILE + it + 2) * 2048;
            #pragma unroll
            for (int i = 0; i < 2; ++i) {
                const int c = i * 512 + tid;
                sreg[2 * i + 0] = src[base4 + 2 * c + 0];
                sreg[2 * i + 1] = src[base4 + 2 * c + 1];
            }
        }

        // ---- (3) GEMM: 32 rows x this wave's 32 cols, K=256 ----
        f32x4 acc[2][2];
        #pragma unroll
        for (int rt = 0; rt < 2; ++rt) {
            acc[rt][0] = (f32x4){0.f, 0.f, 0.f, 0.f};
            acc[rt][1] = (f32x4){0.f, 0.f, 0.f, 0.f};
        }
        {
            const char* ab = lb + abase;
            #pragma unroll
            for (int rt = 0; rt < 2; ++rt) {
                #pragma unroll
                for (int kk = 0; kk < 8; ++kk) {
                    const bf16x8 a = *reinterpret_cast<const bf16x8*>(
                        ab + rt * 16 * PITCH + kk * 64);
                    acc[rt][0] = __builtin_amdgcn_mfma_f32_16x16x32_bf16(a, Bf[kk][0], acc[rt][0], 0, 0, 0);
                    acc[rt][1] = __builtin_amdgcn_mfma_f32_16x16x32_bf16(a, Bf[kk][1], acc[rt][1], 0, 0, 0);
                }
            }
        }

        // ---- (4) tanh epilogue + DPP reduce -> gpartT[it&1][cg][*] ----
        const int gp = it & 1;
        #pragma unroll
        for (int rt = 0; rt < 2; ++rt) {
            float g0 = row16_sum(tanh_pre(acc[rt][0][0] + bs0) * awc0
                               + tanh_pre(acc[rt][1][0] + bs1) * awc1);
            float g1 = row16_sum(tanh_pre(acc[rt][0][1] + bs0) * awc0
                               + tanh_pre(acc[rt][1][1] + bs1) * awc1);
            float g2 = row16_sum(tanh_pre(acc[rt][0][2] + bs0) * awc0
                               + tanh_pre(acc[rt][1][2] + bs1) * awc1);
            float g3 = row16_sum(tanh_pre(acc[rt][0][3] + bs0) * awc0
                               + tanh_pre(acc[rt][1][3] + bs1) * awc1);
            if (l15 == 0) {
                const int r = rt * 16 + (hi << 2);
                *reinterpret_cast<float4*>(&gpartT[gp][cg][r]) = (float4){g0, g1, g2, g3};
            }
        }
        __syncthreads();   // the ONLY barrier per tile
    }

    // ---- drain: evals+wsum for the last tile ----
    do_wsum(NTILE - 1);

    // ---- block epilogue: part_d overlaid on bfb[0] (dead after do_wsum(4)) ----
    {
        float* part_d = reinterpret_cast<float*>(bfb[0]);    // [8][256]
        *reinterpret_cast<float4*>(&part_d[wave * 256 + lane * 4]) =
            (float4){accd[0], accd[1], accd[2], accd[3]};
    }
    __syncthreads();
    if (tid < 256) {
        const float* part_d = reinterpret_cast<const float*>(bfb[0]);
        float s = 0.f;
        #pragma unroll
        for (int w = 0; w < 8; ++w) s += part_d[w * 256 + tid];
        partial_ws[blk * DD + tid] = s;
    }
    if (wave == 0) {
        float s = row16_sum(es_acc);
        s += __shfl_xor(s, 16);
        if (lane == 0) esum_ws[blk] = s;
    }
}

// ---------------------------------------------------------------------------
// finalize: out[b,d] = (sum_i partial) / (sum_i esum + EPS) + sentence[b,d]
// ---------------------------------------------------------------------------
__global__ __launch_bounds__(256) void finalize_kernel(
    const float* __restrict__ sentence, const float* __restrict__ partial_ws,
    const float* __restrict__ esum_ws, float* __restrict__ out)
{
    const int b = blockIdx.x, d = threadIdx.x;
    float es = 0.f, s = 0.f;
    #pragma unroll
    for (int i = 0; i < 8; ++i) {
        es += esum_ws[b * 8 + i];
        s  += partial_ws[(size_t)(b * 8 + i) * DD + d];
    }
    out[b * DD + d] = s / (es + EPSV) + sentence[b * DD + d];
}

extern "C" void kernel_launch(void* const* d_in, const int* in_sizes, int n_in,
                              void* d_out, int out_size, void* d_ws, size_t ws_size,
                              hipStream_t stream)
{
    const float* ctx       = (const float*)d_in[0];
    const float* aspect    = (const float*)d_in[1];
    const float* sentence  = (const float*)d_in[2];
    const int*   mask      = (const int*)  d_in[3];
    const float* context_w = (const float*)d_in[4];
    const float* aspect_w  = (const float*)d_in[5];
    const float* sent_w    = (const float*)d_in[6];
    const float* attend_w  = (const float*)d_in[7];
    float* out = (float*)d_out;

    char* ws = (char*)d_ws;
    ushort* wfrag_ws   = (ushort*)(ws);                           // 131072 B
    float*  bias_part  = (float*) (ws + 131072);                  // 524288 B
    float*  esum_ws    = (float*) (ws + 131072 + 524288);         //   2048 B
    float*  partial_ws = (float*) (ws + 131072 + 524288 + 2048);  // 524288 B

    prep_kernel<<<544, 256, 0, stream>>>(aspect, sentence, context_w, aspect_w, sent_w,
                                         bias_part, wfrag_ws);
    attn_main<<<NBLK, 512, 0, stream>>>(ctx, mask, attend_w, bias_part, wfrag_ws,
                                        partial_ws, esum_ws);
    finalize_kernel<<<BB, 256, 0, stream>>>(sentence, partial_ws, esum_ws, out);
}

// Round 12
// 42.226 us; speedup vs baseline: 1.1258x; 1.0669x over previous
//
#include <hip/hip_runtime.h>
#include <hip/hip_bf16.h>

// Problem dims (fixed by the reference): B=64, T=2048, D=256
#define BB  64
#define TT  2048
#define DD  256
#define EPSV 1e-7f
#define TILE_R 32    // rows per tile
#define NTILE  8     // tiles per block
#define NBLK   512   // blocks: NBLK*NTILE*TILE_R == BB*TT
#define PITCH  528   // LDS row pitch (bytes): bank-spread, additive imm addressing
#define TILEB  16896 // 32 * 528

#define TANH_PRE 2.8853900817779268f   // 2*log2(e): folded into W and bias
#define LOG2E    1.4426950408889634f   // folded into attend_w

typedef __attribute__((ext_vector_type(8))) short bf16x8;   // MFMA A/B fragment (4 VGPR)
typedef __attribute__((ext_vector_type(4))) float f32x4;    // MFMA C/D fragment

__device__ __forceinline__ ushort f2bf(float f) {           // RNE (prep only)
    union { float f; unsigned u; } v; v.f = f;
    unsigned u = v.u;
    unsigned r = (u + 0x7FFFu + ((u >> 16) & 1u)) >> 16;
    return (ushort)r;
}

__device__ __forceinline__ float bf2f(unsigned h16) {       // low 16 bits = bf16
    union { unsigned u; float f; } v; v.u = h16 << 16;
    return v.f;
}

// pack two f32 -> two bf16 (round-half-up): [bf(lo), bf(hi)]
__device__ __forceinline__ unsigned pkbf(float lo, float hi) {
    union { float f; unsigned u; } a, b;
    a.f = lo; b.f = hi;
    return __builtin_amdgcn_perm(b.u + 0x8000u, a.u + 0x8000u, 0x07060302u);
}

// tanh(t) where y = 2*log2(e)*t (scaling pre-folded into MFMA operands):
// tanh(t) = 1 - 2*rcp(exp2(y)+1). Raw v_exp_f32 (NOT the exp2f libcall - R10).
__device__ __forceinline__ float tanh_pre(float y) {
    float e = __builtin_amdgcn_exp2f(y);
    return fmaf(-2.0f, __builtin_amdgcn_rcpf(e + 1.0f), 1.0f);
}

// sum over the 16-lane DPP row via rotations (pure VALU, no LDS traffic)
template<int CTRL>
__device__ __forceinline__ float dpp_rot_add(float x) {
    union { float f; int i; } a; a.f = x;
    int r = __builtin_amdgcn_update_dpp(0, a.i, CTRL, 0xF, 0xF, true);
    union { int i; float f; } b; b.i = r;
    return x + b.f;
}
__device__ __forceinline__ float row16_sum(float x) {
    x = dpp_rot_add<0x121>(x);   // row_ror:1
    x = dpp_rot_add<0x122>(x);   // row_ror:2
    x = dpp_rot_add<0x124>(x);   // row_ror:4
    x = dpp_rot_add<0x128>(x);   // row_ror:8
    return x;                    // all 16 lanes hold the row sum
}

// ---------------------------------------------------------------------------
// prep: blocks 0..511   -> bias partials (block b*8+q covers d in [q*32, q*32+32))
//       blocks 512..543 -> W_frag: context_w (f32) * 2*log2(e) -> bf16 MFMA B-frag order
// ---------------------------------------------------------------------------
__global__ __launch_bounds__(256) void prep_kernel(
    const float* __restrict__ aspect, const float* __restrict__ sentence,
    const float* __restrict__ context_w, const float* __restrict__ aspect_w,
    const float* __restrict__ sent_w,
    float* __restrict__ bias_part, ushort* __restrict__ wfrag_ws)
{
    const int blk = blockIdx.x, tid = threadIdx.x;
    if (blk < 512) {
        const int b = blk >> 3, q = blk & 7, e = tid;
        float s = 0.f;
        #pragma unroll 4
        for (int dd = 0; dd < 32; ++dd) {
            const int d = q * 32 + dd;
            s = fmaf(aspect[b * DD + d],   aspect_w[d * DD + e], s);
            s = fmaf(sentence[b * DD + d], sent_w[d * DD + e],   s);
        }
        bias_part[blk * DD + e] = s;
    } else {
        const int flat = (blk - 512) * 256 + tid;    // 0..8191
        const int lane = flat & 63;
        const int kn   = flat >> 6;
        const int kk   = kn >> 4;
        const int n    = kn & 15;
        const int krow = kk * 32 + ((lane >> 4) << 3);
        const int col  = n * 16 + (lane & 15);
        bf16x8 v;
        #pragma unroll
        for (int j = 0; j < 8; ++j)
            v[j] = (short)f2bf(context_w[(size_t)(krow + j) * DD + col] * TANH_PRE);
        *reinterpret_cast<bf16x8*>(wfrag_ws + (size_t)flat * 8) = v;
    }
}

// ---------------------------------------------------------------------------
// attn_main: 512 blocks x 512 thr (8 waves), 8 tiles of 32 rows.
// Wave grid = 2 ROW-groups x 4 COL-groups (rh = wave>>2 owns 16 rows,
// cg = wave&3 owns 64 cols): each wave reads only ITS 16 A-rows (8 b128
// vs 16) -> A-read LDS traffic HALVES vs the 8-col-group layout.
// Bf = 32 frags = 128 VGPR (MFMA-only; AGPR placement harmless; fits the
// 256 cap of launch_bounds(512,2) with ~190 total footprint).
// QUAD-buffered tiles (pitch 528), ONE barrier/tile, wsum deferred one iter:
//   [wsum(it-1) | convert(it+1) | loads(it+2) | GEMM(it) | tanh->gpartT] BAR
// ---------------------------------------------------------------------------
__global__ __launch_bounds__(512, 2) void attn_main(
    const float* __restrict__ ctx, const int* __restrict__ mask,
    const float* __restrict__ attend_w,
    const float* __restrict__ bias_part, const ushort* __restrict__ wfrag_ws,
    float* __restrict__ partial_ws, float* __restrict__ esum_ws)
{
    __shared__ __align__(16) char bfb[4][TILEB];   // 4 x 16.9KB bf16 tiles
    __shared__ float gpartT[2][4][TILE_R];         // [phase][cg][row]
    __shared__ float bias_lds[256];
    __shared__ float aw_lds[256];
    __shared__ float mask_lds[256];

    const int tid  = threadIdx.x;
    const int wave = tid >> 6;
    const int lane = tid & 63;
    const int blk  = blockIdx.x;
    const int b    = blk >> 3;               // 8 blocks per batch element
    const int rh   = wave >> 2;              // row half: 16 rows
    const int cg   = wave & 3;               // col group: 64 cols
    const int l15  = lane & 15, hi = lane >> 4;

    if (tid < 256) {
        float bs = 0.f;
        #pragma unroll
        for (int q = 0; q < 8; ++q) bs += bias_part[(b * 8 + q) * DD + tid];
        bias_lds[tid] = bs * TANH_PRE;
    } else {
        const int m = tid - 256;
        aw_lds[m]   = attend_w[m] * LOG2E;
        mask_lds[m] = (float)mask[blk * 256 + m];
    }

    // ---- preload this wave's 32 B-fragments (cols cg*64 .. +63): 128 VGPR ----
    bf16x8 Bf[8][4];
    {
        const bf16x8* wf = reinterpret_cast<const bf16x8*>(wfrag_ws);
        #pragma unroll
        for (int kk = 0; kk < 8; ++kk) {
            #pragma unroll
            for (int n = 0; n < 4; ++n)
                Bf[kk][n] = wf[(kk * 16 + cg * 4 + n) * 64 + lane];
        }
    }

    const float4* src = reinterpret_cast<const float4*>(ctx);
    // convert-phase destinations (additive, no XOR)
    const int crow0 = tid >> 5,          c80 = tid & 31;
    const int crow1 = (512 + tid) >> 5,  c81 = (512 + tid) & 31;
    const int coff0 = crow0 * PITCH + c80 * 16;
    const int coff1 = crow1 * PITCH + c81 * 16;
    // GEMM A-read lane base (this wave's 16 rows); reads at imm kk*64
    const int abase = (rh * 16 + l15) * PITCH + hi * 16;
    // wsum read base; reads at imm rr*PITCH
    const int wbase = wave * 4 * PITCH + lane * 8;

    // ---- prologue: load tile 0, convert -> buf0, issue tile 1 loads ----
    float4 sreg[4];
    {
        const size_t base4 = (size_t)(blk * NTILE) * 2048;
        #pragma unroll
        for (int i = 0; i < 2; ++i) {
            const int c = i * 512 + tid;
            sreg[2 * i + 0] = src[base4 + 2 * c + 0];
            sreg[2 * i + 1] = src[base4 + 2 * c + 1];
        }
        char* dst = bfb[0];
        #pragma unroll
        for (int i = 0; i < 2; ++i) {
            uint4 u;
            u.x = pkbf(sreg[2 * i].x,     sreg[2 * i].y);
            u.y = pkbf(sreg[2 * i].z,     sreg[2 * i].w);
            u.z = pkbf(sreg[2 * i + 1].x, sreg[2 * i + 1].y);
            u.w = pkbf(sreg[2 * i + 1].z, sreg[2 * i + 1].w);
            *reinterpret_cast<uint4*>(dst + (i ? coff1 : coff0)) = u;
        }
        const size_t b1 = (size_t)(blk * NTILE + 1) * 2048;
        #pragma unroll
        for (int i = 0; i < 2; ++i) {
            const int c = i * 512 + tid;
            sreg[2 * i + 0] = src[b1 + 2 * c + 0];
            sreg[2 * i + 1] = src[b1 + 2 * c + 1];
        }
    }
    __syncthreads();

    // loop-invariant epilogue constants (this wave's 4 col-frags)
    float bsn[4], awn[4];
    #pragma unroll
    for (int n = 0; n < 4; ++n) {
        const int c = (cg * 4 + n) * 16 + l15;
        bsn[n] = bias_lds[c];
        awn[n] = aw_lds[c];
    }

    float accd[4] = {0.f, 0.f, 0.f, 0.f};
    float es_acc = 0.f;

    // deferred evals + weighted sum for tile t (reads gpartT[t&1], bfb[t&3])
    auto do_wsum = [&](int t) {
        const char* pb = bfb[t & 3] + wbase;
        const int gp = t & 1;
        const int erow = lane & 31;
        float gsum = 0.f;
        #pragma unroll
        for (int c = 0; c < 4; ++c) gsum += gpartT[gp][c][erow];
        const float ev = __builtin_amdgcn_exp2f(gsum) * mask_lds[t * TILE_R + erow];
        es_acc += (lane < 32) ? ev : 0.f;
        #pragma unroll
        for (int rr = 0; rr < 4; ++rr) {
            const int r = wave * 4 + rr;
            const float e = __shfl(ev, r);   // uniform index -> readlane broadcast
            const uint2 hv = *reinterpret_cast<const uint2*>(pb + rr * PITCH);
            accd[0] = fmaf(bf2f(hv.x & 0xffffu), e, accd[0]);
            accd[1] = fmaf(bf2f(hv.x >> 16),     e, accd[1]);
            accd[2] = fmaf(bf2f(hv.y & 0xffffu), e, accd[2]);
            accd[3] = fmaf(bf2f(hv.y >> 16),     e, accd[3]);
        }
    };

    for (int it = 0; it < NTILE; ++it) {
        const char* lb = bfb[it & 3];

        // ---- (0) deferred evals+wsum for tile it-1 ----
        if (it > 0) do_wsum(it - 1);

        // ---- (1) convert sreg (tile it+1 data) -> buf[(it+1)&3] ----
        if (it + 1 < NTILE) {
            char* dst = bfb[(it + 1) & 3];
            #pragma unroll
            for (int i = 0; i < 2; ++i) {
                uint4 u;
                u.x = pkbf(sreg[2 * i].x,     sreg[2 * i].y);
                u.y = pkbf(sreg[2 * i].z,     sreg[2 * i].w);
                u.z = pkbf(sreg[2 * i + 1].x, sreg[2 * i + 1].y);
                u.w = pkbf(sreg[2 * i + 1].z, sreg[2 * i + 1].w);
                *reinterpret_cast<uint4*>(dst + (i ? coff1 : coff0)) = u;
            }
        }
        // ---- (2) issue tile it+2 global loads ----
        if (it + 2 < NTILE) {
            const size_t base4 = (size_t)(blk * NTILE + it + 2) * 2048;
            #pragma unroll
            for (int i = 0; i < 2; ++i) {
                const int c = i * 512 + tid;
                sreg[2 * i + 0] = src[base4 + 2 * c + 0];
                sreg[2 * i + 1] = src[base4 + 2 * c + 1];
            }
        }

        // ---- (3) GEMM: this wave's 16 rows x 64 cols, K=256 (8 A-reads) ----
        f32x4 acc[4];
        #pragma unroll
        for (int n = 0; n < 4; ++n) acc[n] = (f32x4){0.f, 0.f, 0.f, 0.f};
        {
            const char* ab = lb + abase;
            #pragma unroll
            for (int kk = 0; kk < 8; ++kk) {
                const bf16x8 a = *reinterpret_cast<const bf16x8*>(ab + kk * 64);
                #pragma unroll
                for (int n = 0; n < 4; ++n)
                    acc[n] = __builtin_amdgcn_mfma_f32_16x16x32_bf16(a, Bf[kk][n], acc[n], 0, 0, 0);
            }
        }

        // ---- (4) tanh epilogue + DPP reduce -> gpartT[it&1][cg][rh rows] ----
        const int gp = it & 1;
        {
            float g[4];
            #pragma unroll
            for (int j = 0; j < 4; ++j) {
                float gv = tanh_pre(acc[0][j] + bsn[0]) * awn[0]
                         + tanh_pre(acc[1][j] + bsn[1]) * awn[1]
                         + tanh_pre(acc[2][j] + bsn[2]) * awn[2]
                         + tanh_pre(acc[3][j] + bsn[3]) * awn[3];
                g[j] = row16_sum(gv);
            }
            if (l15 == 0) {
                const int r = rh * 16 + (hi << 2);   // rows r..r+3
                *reinterpret_cast<float4*>(&gpartT[gp][cg][r]) =
                    (float4){g[0], g[1], g[2], g[3]};
            }
        }
        __syncthreads();   // the ONLY barrier per tile
    }

    // ---- drain: evals+wsum for the last tile ----
    do_wsum(NTILE - 1);

    // ---- block epilogue: part_d overlaid on bfb[0] (dead after do_wsum(4)) ----
    {
        float* part_d = reinterpret_cast<float*>(bfb[0]);    // [8][256]
        *reinterpret_cast<float4*>(&part_d[wave * 256 + lane * 4]) =
            (float4){accd[0], accd[1], accd[2], accd[3]};
    }
    __syncthreads();
    if (tid < 256) {
        const float* part_d = reinterpret_cast<const float*>(bfb[0]);
        float s = 0.f;
        #pragma unroll
        for (int w = 0; w < 8; ++w) s += part_d[w * 256 + tid];
        partial_ws[blk * DD + tid] = s;
    }
    if (wave == 0) {
        float s = row16_sum(es_acc);
        s += __shfl_xor(s, 16);
        if (lane == 0) esum_ws[blk] = s;
    }
}

// ---------------------------------------------------------------------------
// finalize: out[b,d] = (sum_i partial) / (sum_i esum + EPS) + sentence[b,d]
// ---------------------------------------------------------------------------
__global__ __launch_bounds__(256) void finalize_kernel(
    const float* __restrict__ sentence, const float* __restrict__ partial_ws,
    const float* __restrict__ esum_ws, float* __restrict__ out)
{
    const int b = blockIdx.x, d = threadIdx.x;
    float es = 0.f, s = 0.f;
    #pragma unroll
    for (int i = 0; i < 8; ++i) {
        es += esum_ws[b * 8 + i];
        s  += partial_ws[(size_t)(b * 8 + i) * DD + d];
    }
    out[b * DD + d] = s / (es + EPSV) + sentence[b * DD + d];
}

extern "C" void kernel_launch(void* const* d_in, const int* in_sizes, int n_in,
                              void* d_out, int out_size, void* d_ws, size_t ws_size,
                              hipStream_t stream)
{
    const float* ctx       = (const float*)d_in[0];
    const float* aspect    = (const float*)d_in[1];
    const float* sentence  = (const float*)d_in[2];
    const int*   mask      = (const int*)  d_in[3];
    const float* context_w = (const float*)d_in[4];
    const float* aspect_w  = (const float*)d_in[5];
    const float* sent_w    = (const float*)d_in[6];
    const float* attend_w  = (const float*)d_in[7];
    float* out = (float*)d_out;

    char* ws = (char*)d_ws;
    ushort* wfrag_ws   = (ushort*)(ws);                           // 131072 B
    float*  bias_part  = (float*) (ws + 131072);                  // 524288 B
    float*  esum_ws    = (float*) (ws + 131072 + 524288);         //   2048 B
    float*  partial_ws = (float*) (ws + 131072 + 524288 + 2048);  // 524288 B

    prep_kernel<<<544, 256, 0, stream>>>(aspect, sentence, context_w, aspect_w, sent_w,
                                         bias_part, wfrag_ws);
    attn_main<<<NBLK, 512, 0, stream>>>(ctx, mask, attend_w, bias_part, wfrag_ws,
                                        partial_ws, esum_ws);
    finalize_kernel<<<BB, 256, 0, stream>>>(sentence, partial_ws, esum_ws, out);
}